// Round 3
// baseline (829.060 us; speedup 1.0000x reference)
//
#include <hip/hip_runtime.h>
#include <hip/hip_bf16.h>
#include <hip/hip_cooperative_groups.h>

namespace cg = cooperative_groups;

#define B 32
#define C_IN 192
#define T 8192
#define H 192
#define N_PH 1024
#define OUT 4
#define ROW_MAX 7168          // max total frames = 7 * 1024
#define PROWS (N_PH + 2)      // padded rows: t = -1 .. N_PH
#define ROWP (2 * H)          // row pitch: hi plane [0,H), lo plane [H,2H)
#define NCU 256               // MI355X CUs

typedef __attribute__((ext_vector_type(8))) short short8;
typedef __attribute__((ext_vector_type(4))) float f32x4;
typedef unsigned short ushort_t;

__device__ inline ushort_t f2bf(float f) {
    unsigned u = __builtin_bit_cast(unsigned, f);
    unsigned r = u + 0x7fffu + ((u >> 16) & 1u);   // RNE
    return (ushort_t)(r >> 16);
}
__device__ inline float bf2f(ushort_t h) {
    unsigned u = ((unsigned)h) << 16;
    return __builtin_bit_cast(float, u);
}
// split x into hi+lo bf16 pair (~17-bit effective mantissa) -- accuracy-mandatory
__device__ inline void split_bf(float x, ushort_t& hi, ushort_t& lo) {
    hi = f2bf(x);
    lo = f2bf(x - bf2f(hi));
}

// ---------------- shared-memory union across pipeline stages ----------------
struct S1 { int e_s[N_PH]; int part[256]; float row[ROW_MAX]; };   // 33.8 KB
struct S2 { float tile[32][33]; };                                  // 4.2 KB
struct S3 { float ep[64][193]; float g_s[H]; float b_s[H];
            float m_s[64]; float mstat[64]; float rstat[64]; };     // 51.7 KB
union __align__(16) SharedU { S1 s1; S2 s2; S3 s3; };

// ---------------- weight prep: MFMA-fragment-ordered, split hi/lo -----------
// Fragment slot (kt, s, nt): 512 ushort = lane*8 + j.
// Stored value: w[o = nt*16 + (lane&15)][k_in_tap = s*32 + (lane>>4)*8 + j][tap kt]
__device__ inline void wfrag_one(const float* __restrict__ w, ushort_t* __restrict__ wtf,
                                 int taps, int idx, int ntot) {
    int j  = idx & 7;
    int l  = (idx >> 3) & 63;
    int slot = idx >> 9;             // (kt*6 + s)*12 + nt
    int nt = slot % 12;
    int ss = (slot / 12) % 6;
    int kt = slot / 72;
    int o  = nt * 16 + (l & 15);
    int i  = ss * 32 + ((l >> 4) << 3) + j;
    float v = (taps == 1) ? w[o * C_IN + i] : w[(o * H + i) * 3 + kt];
    ushort_t hi, lo;
    split_bf(v, hi, lo);
    wtf[idx] = hi;
    wtf[idx + ntot] = lo;
}

// ---------------- fused MFMA GEMM core: conv(taps)+bias [+relu+LN] +mask [+proj] ----
#define LOADOPS(IT, AH0, AL0, AH1, AL1, BH, BL) do {                              \
    int kt_ = (IT) / 6, s_ = (IT) - kt_ * 6;                                      \
    const ushort_t* arow_ = inb + (long)(trow + kt_ - pad) * ROWP + s_ * 32 + kg; \
    AH0 = *(const short8*)(arow_);                                                \
    AL0 = *(const short8*)(arow_ + H);                                            \
    AH1 = *(const short8*)(arow_ + 16 * ROWP);                                    \
    AL1 = *(const short8*)(arow_ + 16 * ROWP + H);                                \
    const ushort_t* wb_ = wt + ((size_t)((kt_ * 6 + s_) * 12 + nhalf * 6) << 9)   \
                        + (lane << 3);                                            \
    _Pragma("unroll") for (int n_ = 0; n_ < 6; ++n_) {                            \
        BH[n_] = *(const short8*)(wb_ + (n_ << 9));                               \
        BL[n_] = *(const short8*)(wb_ + (n_ << 9) + ntotw); }                     \
} while (0)

#define DOMFMA(AH0, AL0, AH1, AL1, BH, BL) do {                                             \
    _Pragma("unroll") for (int n_ = 0; n_ < 6; ++n_) {                                      \
        acc[0][n_] = __builtin_amdgcn_mfma_f32_16x16x32_bf16(AH0, BH[n_], acc[0][n_], 0,0,0); \
        acc[0][n_] = __builtin_amdgcn_mfma_f32_16x16x32_bf16(AL0, BH[n_], acc[0][n_], 0,0,0); \
        acc[0][n_] = __builtin_amdgcn_mfma_f32_16x16x32_bf16(AH0, BL[n_], acc[0][n_], 0,0,0); \
        acc[1][n_] = __builtin_amdgcn_mfma_f32_16x16x32_bf16(AH1, BH[n_], acc[1][n_], 0,0,0); \
        acc[1][n_] = __builtin_amdgcn_mfma_f32_16x16x32_bf16(AL1, BH[n_], acc[1][n_], 0,0,0); \
        acc[1][n_] = __builtin_amdgcn_mfma_f32_16x16x32_bf16(AH1, BL[n_], acc[1][n_], 0,0,0); } \
} while (0)

__device__ void gemm_core(SharedU& sh, int tix,
    const ushort_t* __restrict__ in, int in_rows,
    const ushort_t* __restrict__ wt,
    const float* __restrict__ bias,
    const float* __restrict__ mask,
    const float* __restrict__ g, const float* __restrict__ beta,
    ushort_t* __restrict__ out,
    const float* __restrict__ lw, const float* __restrict__ lb,
    float* __restrict__ fout,
    int taps, int do_ln, int nmask, int fin)
{
    int b  = tix >> 4;                  // 512 tiles = 32 batches x 16 t-tiles
    int t0 = (tix & 15) * 64;
    int tid = threadIdx.x;
    int lane = tid & 63;
    int wv = tid >> 6;
    int mhalf = wv & 1;
    int nhalf = wv >> 1;

    float (&ep)[64][193] = sh.s3.ep;
    float* g_s  = sh.s3.g_s;
    float* b_s  = sh.s3.b_s;
    float* m_s  = sh.s3.m_s;
    float* mstat = sh.s3.mstat;
    float* rstat = sh.s3.rstat;

    __syncthreads();   // protect LDS against previous tile's epilogue readers

    if (tid < H) { g_s[tid] = do_ln ? g[tid] : 1.f; b_s[tid] = do_ln ? beta[tid] : 0.f; }
    if (tid < 64) m_s[tid] = mask[b * N_PH + t0 + tid];

    // zero halo rows (t=-1 and t=N_PH), both planes (skip in fin mode: no store)
    short8 z8 = {0, 0, 0, 0, 0, 0, 0, 0};
    if (!fin) {
        if (t0 == 0 && tid < ROWP / 8)
            *(short8*)(out + (size_t)b * PROWS * ROWP + tid * 8) = z8;
        if (t0 == N_PH - 64 && tid < ROWP / 8)
            *(short8*)(out + ((size_t)b * PROWS + N_PH + 1) * ROWP + tid * 8) = z8;
    }

    int m  = lane & 15;                 // A time-row / B channel / D col
    int kg = (lane >> 4) << 3;          // k offset within 32-step: 0,8,16,24
    int ntotw = taps * 36864;           // hi-plane size; lo at +ntotw
    int pad = taps >> 1;

    const ushort_t* inb = in + (size_t)b * in_rows * ROWP;
    int trow = t0 + mhalf * 32 + m;     // +16 for second A-frag

    f32x4 acc[2][6];
#pragma unroll
    for (int ntl = 0; ntl < 6; ++ntl) {
        float bb = bias[(nhalf * 6 + ntl) * 16 + m];
        acc[0][ntl] = (f32x4){bb, bb, bb, bb};
        acc[1][ntl] = (f32x4){bb, bb, bb, bb};
    }

    // K-loop with register double-buffered prefetch (iters = 6 or 18, even)
    short8 pah0, pal0, pah1, pal1, pbh[6], pbl[6];
    short8 qah0, qal0, qah1, qal1, qbh[6], qbl[6];
    int iters = taps * 6;
    LOADOPS(0, pah0, pal0, pah1, pal1, pbh, pbl);
#pragma unroll 1
    for (int it = 0; it < iters; it += 2) {
        LOADOPS(it + 1, qah0, qal0, qah1, qal1, qbh, qbl);
        DOMFMA(pah0, pal0, pah1, pal1, pbh, pbl);
        if (it + 2 < iters) LOADOPS(it + 2, pah0, pal0, pah1, pal1, pbh, pbl);
        DOMFMA(qah0, qal0, qah1, qal1, qbh, qbl);
    }

    __syncthreads();   // covers g_s/b_s/m_s staging

    // write pre-LN (or final-masked) values to LDS, C/D layout -> [time][channel]
    int rbase = (lane >> 4) << 2;
#pragma unroll
    for (int mh = 0; mh < 2; ++mh) {
#pragma unroll
        for (int ntl = 0; ntl < 6; ++ntl) {
            int o = (nhalf * 6 + ntl) * 16 + m;
#pragma unroll
            for (int r = 0; r < 4; ++r) {
                int t_loc = mhalf * 32 + mh * 16 + rbase + r;
                float mm = m_s[t_loc];
                float v = acc[mh][ntl][r];
                if (do_ln) {
                    v = fmaxf(v * mm, 0.f) * mm;     // relu(conv*mask)*mask -> LN input
                } else {
                    for (int q = 0; q < nmask; ++q) v *= mm;
                }
                ep[t_loc][o] = v;
            }
        }
    }
    __syncthreads();

    // LN stats: one thread per time row
    if (do_ln && tid < 64) {
        float s = 0.f, ss = 0.f;
        for (int c = 0; c < H; ++c) {
            float v = ep[tid][c];
            s += v;
            ss += v * v;
        }
        float mean = s * (1.f / (float)H);
        mstat[tid] = mean;
        rstat[tid] = rsqrtf(ss * (1.f / (float)H) - mean * mean + 1e-5f);
    }
    __syncthreads();

    int row = tid >> 2;
    int q = tid & 3;
    if (fin) {
        // fused final projection: p[o] = (sum_c lw[o][c] * (ln(c)*mk) + lb[o]) * mk
        float mean = mstat[row], rstd = rstat[row], mk = m_s[row];
        float a0 = 0.f, a1 = 0.f, a2 = 0.f, a3 = 0.f;
#pragma unroll 1
        for (int c = q * 48; c < q * 48 + 48; ++c) {
            float y = ((ep[row][c] - mean) * rstd * g_s[c] + b_s[c]) * mk;
            a0 += lw[0 * H + c] * y;
            a1 += lw[1 * H + c] * y;
            a2 += lw[2 * H + c] * y;
            a3 += lw[3 * H + c] * y;
        }
        a0 += __shfl_xor(a0, 1); a0 += __shfl_xor(a0, 2);
        a1 += __shfl_xor(a1, 1); a1 += __shfl_xor(a1, 2);
        a2 += __shfl_xor(a2, 1); a2 += __shfl_xor(a2, 2);
        a3 += __shfl_xor(a3, 1); a3 += __shfl_xor(a3, 2);
        if (q == 0) {
            int t = t0 + row;
            float* ob = fout + (size_t)b * OUT * N_PH + t;
            ob[0 * N_PH] = (a0 + lb[0]) * mk;
            ob[1 * N_PH] = (a1 + lb[1]) * mk;
            ob[2 * N_PH] = (a2 + lb[2]) * mk;
            ob[3 * N_PH] = (a3 + lb[3]) * mk;
        }
        return;
    }

    // store: 4 threads per row, 48 channels each, split bf16
    float mean = 0.f, rstd = 1.f, mfac = 1.f;
    if (do_ln) {
        mean = mstat[row];
        rstd = rstat[row];
        float mk = m_s[row];
        mfac = (nmask == 2) ? mk * mk : mk;
    }
    ushort_t* orow = out + ((size_t)b * PROWS + t0 + row + 1) * ROWP + q * 48;
#pragma unroll
    for (int i0 = 0; i0 < 48; i0 += 8) {
        ushort_t th[8], tl[8];
#pragma unroll
        for (int k2 = 0; k2 < 8; ++k2) {
            int c = q * 48 + i0 + k2;
            float v = ep[row][c];
            float y = do_ln ? ((v - mean) * rstd * g_s[c] + b_s[c]) * mfac : v;
            split_bf(y, th[k2], tl[k2]);
        }
        *(short8*)(orow + i0) = *(short8*)th;
        *(short8*)(orow + H + i0) = *(short8*)tl;
    }
}

// ---------------- the whole pipeline as ONE cooperative kernel ----------------
__global__ __launch_bounds__(256) void mega_kernel(
    const float* __restrict__ x, const float* __restrict__ x_mask,
    const int* __restrict__ wdur,
    const float* __restrict__ pre_w, const float* __restrict__ pre_b,
    const float* __restrict__ conv0_w, const float* __restrict__ conv0_b,
    const float* __restrict__ ln0_g, const float* __restrict__ ln0_b,
    const float* __restrict__ conv1_w, const float* __restrict__ conv1_b,
    const float* __restrict__ ln1_g, const float* __restrict__ ln1_b,
    const float* __restrict__ lin_w, const float* __restrict__ lin_b,
    float* __restrict__ out,
    float* __restrict__ spec, ushort_t* __restrict__ bufA, ushort_t* __restrict__ bufB,
    ushort_t* __restrict__ wpre, ushort_t* __restrict__ w0t, ushort_t* __restrict__ w1t,
    int* __restrict__ ends)
{
    cg::grid_group grid = cg::this_grid();
    int blk = blockIdx.x;
    int nblk = gridDim.x;
    int tid = threadIdx.x;
    __shared__ SharedU sh;
    ushort_t* specT = bufB;   // specT aliases bufB (consumed before conv0 writes bufB)

    // ---- stage 0: weight fragments (all blocks) + duration scan (blocks < B) ----
    {
        const int n1 = 36864, n3 = 110592;
        for (int idx = blk * 256 + tid; idx < n1 + 2 * n3; idx += nblk * 256) {
            int i2 = idx;
            if (i2 < n1)              wfrag_one(pre_w, wpre, 1, i2, n1);
            else if ((i2 -= n1) < n3) wfrag_one(conv0_w, w0t, 3, i2, n3);
            else                      wfrag_one(conv1_w, w1t, 3, i2 - n3, n3);
        }
        if (blk < B) {
            int b = blk;
            int* part = sh.s1.part;
            int4 w4 = ((const int4*)(wdur + b * N_PH))[tid];
            int c0 = w4.x, c1 = c0 + w4.y, c2 = c1 + w4.z, c3 = c2 + w4.w;
            part[tid] = c3;
            __syncthreads();
            for (int off = 1; off < 256; off <<= 1) {
                int v = (tid >= off) ? part[tid - off] : 0;
                __syncthreads();
                part[tid] += v;
                __syncthreads();
            }
            int pre = tid ? part[tid - 1] : 0;
            int4 e4;
            e4.x = pre + c0; e4.y = pre + c1; e4.z = pre + c2; e4.w = pre + c3;
            ((int4*)(ends + b * N_PH))[tid] = e4;
        }
    }
    __threadfence();
    grid.sync();

    // ---- stage 1: segment mean (6144 rows, grid-strided) ----
    for (int bc = blk; bc < B * C_IN; bc += nblk) {
        int b = bc / C_IN;
        int c = bc - b * C_IN;
        ((int4*)sh.s1.e_s)[tid] = ((const int4*)(ends + b * N_PH))[tid];
        __syncthreads();
        int emax = sh.s1.e_s[N_PH - 1];           // <= ROW_MAX (w < 8)
        const float4* xr4 = (const float4*)(x + ((size_t)b * C_IN + c) * T);
        float4* row4 = (float4*)sh.s1.row;
        int nv = (emax + 3) >> 2;
        for (int t2 = tid; t2 < nv; t2 += 256) row4[t2] = xr4[t2];
        __syncthreads();
        float* sp = spec + ((size_t)b * C_IN + c) * N_PH;
        for (int j = tid; j < N_PH; j += 256) {
            int s0 = j ? sh.s1.e_s[j - 1] : 0;
            int e0 = sh.s1.e_s[j];
            float sum = 0.f;
            for (int t2 = s0; t2 < e0; ++t2) sum += sh.s1.row[t2];
            sp[j] = (e0 > s0) ? sum / (float)(e0 - s0) : 0.f;
        }
        __syncthreads();   // before LDS reuse next iteration
    }
    __threadfence();
    grid.sync();

    // ---- stage 2: transpose spec -> time-major split bf16 (6144 tiles) ----
    for (int tix2 = blk; tix2 < (N_PH / 32) * (C_IN / 32) * B; tix2 += nblk) {
        int jt = (tix2 & 31) * 32;
        int rem = tix2 >> 5;
        int ct = (rem % (C_IN / 32)) * 32;
        int b  = rem / (C_IN / 32);
        int tx = tid & 31;
        int ty = tid >> 5;     // 8 rows per pass
        const float* sb = spec + ((size_t)b * C_IN + ct) * N_PH + jt;
        for (int r = ty; r < 32; r += 8) sh.s2.tile[r][tx] = sb[(size_t)r * N_PH + tx];
        __syncthreads();
        ushort_t* ob = specT + ((size_t)b * N_PH + jt) * ROWP + ct;
        for (int r = ty; r < 32; r += 8) {
            ushort_t hi, lo;
            split_bf(sh.s2.tile[tx][r], hi, lo);
            ob[(size_t)r * ROWP + tx] = hi;
            ob[(size_t)r * ROWP + H + tx] = lo;
        }
        __syncthreads();   // before LDS reuse next iteration
    }
    __threadfence();
    grid.sync();

    // ---- stage 3: pre linear (taps=1): specT -> bufA ----
    for (int tix = blk; tix < 16 * B; tix += nblk)
        gemm_core(sh, tix, specT, N_PH, wpre, pre_b, x_mask, ln0_g, ln0_b, bufA,
                  nullptr, nullptr, nullptr, 1, 0, 1, 0);
    __threadfence();
    grid.sync();

    // ---- stage 4: conv block 0: bufA -> bufB ----
    for (int tix = blk; tix < 16 * B; tix += nblk)
        gemm_core(sh, tix, bufA + ROWP, PROWS, w0t, conv0_b, x_mask, ln0_g, ln0_b, bufB,
                  nullptr, nullptr, nullptr, 3, 1, 2, 0);
    __threadfence();
    grid.sync();

    // ---- stage 5: conv block 1 + fused final projection: bufB -> out ----
    for (int tix = blk; tix < 16 * B; tix += nblk)
        gemm_core(sh, tix, bufB + ROWP, PROWS, w1t, conv1_b, x_mask, ln1_g, ln1_b, bufA,
                  lin_w, lin_b, out, 3, 1, 1, 1);
}

// ================= fallback path: proven round-1 standalone kernels =================
__global__ __launch_bounds__(256) void segmean_kernel(const float* __restrict__ x,
                                                      const int* __restrict__ wdur,
                                                      float* __restrict__ spec) {
    int bc = blockIdx.x;
    int b = bc / C_IN;
    int c = bc % C_IN;
    __shared__ SharedU sh;
    int tid = threadIdx.x;
    int4 w4 = ((const int4*)(wdur + b * N_PH))[tid];
    int c0 = w4.x, c1 = c0 + w4.y, c2 = c1 + w4.z, c3 = c2 + w4.w;
    sh.s1.part[tid] = c3;
    __syncthreads();
    for (int off = 1; off < 256; off <<= 1) {
        int v = (tid >= off) ? sh.s1.part[tid - off] : 0;
        __syncthreads();
        sh.s1.part[tid] += v;
        __syncthreads();
    }
    int pre = tid ? sh.s1.part[tid - 1] : 0;
    sh.s1.e_s[4 * tid + 0] = pre + c0;
    sh.s1.e_s[4 * tid + 1] = pre + c1;
    sh.s1.e_s[4 * tid + 2] = pre + c2;
    sh.s1.e_s[4 * tid + 3] = pre + c3;
    __syncthreads();
    int emax = sh.s1.e_s[N_PH - 1];
    const float4* xr4 = (const float4*)(x + ((size_t)b * C_IN + c) * T);
    float4* row4 = (float4*)sh.s1.row;
    int nv = (emax + 3) >> 2;
    for (int t2 = tid; t2 < nv; t2 += 256) row4[t2] = xr4[t2];
    __syncthreads();
    float* sp = spec + ((size_t)b * C_IN + c) * N_PH;
    for (int j = tid; j < N_PH; j += 256) {
        int s0 = j ? sh.s1.e_s[j - 1] : 0;
        int e0 = sh.s1.e_s[j];
        float sum = 0.f;
        for (int t2 = s0; t2 < e0; ++t2) sum += sh.s1.row[t2];
        sp[j] = (e0 > s0) ? sum / (float)(e0 - s0) : 0.f;
    }
}

__global__ __launch_bounds__(256) void transpose_spec_kernel(const float* __restrict__ spec,
                                                             ushort_t* __restrict__ specT) {
    int jt = blockIdx.x * 32;
    int ct = (blockIdx.y % (C_IN / 32)) * 32;
    int b  = blockIdx.y / (C_IN / 32);
    __shared__ SharedU sh;
    int tx = threadIdx.x & 31;
    int ty = threadIdx.x >> 5;
    const float* sb = spec + ((size_t)b * C_IN + ct) * N_PH + jt;
    for (int r = ty; r < 32; r += 8) sh.s2.tile[r][tx] = sb[(size_t)r * N_PH + tx];
    __syncthreads();
    ushort_t* ob = specT + ((size_t)b * N_PH + jt) * ROWP + ct;
    for (int r = ty; r < 32; r += 8) {
        ushort_t hi, lo;
        split_bf(sh.s2.tile[tx][r], hi, lo);
        ob[(size_t)r * ROWP + tx] = hi;
        ob[(size_t)r * ROWP + H + tx] = lo;
    }
}

__global__ void wfrag_all_kernel(const float* __restrict__ pw, const float* __restrict__ w0,
                                 const float* __restrict__ w1,
                                 ushort_t* __restrict__ wpre, ushort_t* __restrict__ w0t,
                                 ushort_t* __restrict__ w1t) {
    int idx = blockIdx.x * 256 + threadIdx.x;
    const int n1 = 36864, n3 = 110592;
    if (idx < n1) { wfrag_one(pw, wpre, 1, idx, n1); return; }
    idx -= n1;
    if (idx < n3) { wfrag_one(w0, w0t, 3, idx, n3); return; }
    idx -= n3;
    if (idx < n3) wfrag_one(w1, w1t, 3, idx, n3);
}

__global__ __launch_bounds__(256) void gemm_fused_kernel(
    const ushort_t* __restrict__ in, int in_rows,
    const ushort_t* __restrict__ wt,
    const float* __restrict__ bias,
    const float* __restrict__ mask,
    const float* __restrict__ g, const float* __restrict__ beta,
    ushort_t* __restrict__ out,
    const float* __restrict__ lw, const float* __restrict__ lb,
    float* __restrict__ fout,
    int taps, int do_ln, int nmask, int fin)
{
    __shared__ SharedU sh;
    int tix = blockIdx.y * (N_PH / 64) + blockIdx.x;   // b*16 + t-tile
    gemm_core(sh, tix, in, in_rows, wt, bias, mask, g, beta, out, lw, lb, fout,
              taps, do_ln, nmask, fin);
}

extern "C" void kernel_launch(void* const* d_in, const int* in_sizes, int n_in,
                              void* d_out, int out_size, void* d_ws, size_t ws_size,
                              hipStream_t stream) {
    const float* x      = (const float*)d_in[0];
    const float* x_mask = (const float*)d_in[1];
    const int*   w      = (const int*)d_in[2];
    const float* pre_w  = (const float*)d_in[3];
    const float* pre_b  = (const float*)d_in[4];
    const float* conv0_w = (const float*)d_in[5];
    const float* conv0_b = (const float*)d_in[6];
    const float* ln0_g   = (const float*)d_in[7];
    const float* ln0_b   = (const float*)d_in[8];
    const float* conv1_w = (const float*)d_in[9];
    const float* conv1_b = (const float*)d_in[10];
    const float* ln1_g   = (const float*)d_in[11];
    const float* ln1_b   = (const float*)d_in[12];
    const float* lin_w   = (const float*)d_in[13];
    const float* lin_b   = (const float*)d_in[14];
    float* out = (float*)d_out;

    // workspace layout
    char* ws = (char*)d_ws;
    size_t off = 0;
    float* spec = (float*)(ws + off);       off += (size_t)B * C_IN * N_PH * sizeof(float);
    ushort_t* bufA = (ushort_t*)(ws + off); off += (size_t)B * PROWS * ROWP * sizeof(ushort_t);
    ushort_t* bufB = (ushort_t*)(ws + off); off += (size_t)B * PROWS * ROWP * sizeof(ushort_t);
    ushort_t* wpre = (ushort_t*)(ws + off); off += (size_t)2 * 36864 * sizeof(ushort_t);
    ushort_t* w0t  = (ushort_t*)(ws + off); off += (size_t)2 * 110592 * sizeof(ushort_t);
    ushort_t* w1t  = (ushort_t*)(ws + off); off += (size_t)2 * 110592 * sizeof(ushort_t);
    int* ends      = (int*)(ws + off);      off += (size_t)B * N_PH * sizeof(int);
    ushort_t* specT = bufB;

    // ---- try the fused cooperative path, grid clamped to runtime occupancy ----
    int maxb = 0;
    hipError_t qe = hipOccupancyMaxActiveBlocksPerMultiprocessor(&maxb, mega_kernel, 256, 0);
    if (qe != hipSuccess || maxb < 1) maxb = 1;
    int nblk = maxb * NCU;
    if (nblk > 512) nblk = 512;

    void* kargs[] = {
        (void*)&x, (void*)&x_mask, (void*)&w,
        (void*)&pre_w, (void*)&pre_b,
        (void*)&conv0_w, (void*)&conv0_b, (void*)&ln0_g, (void*)&ln0_b,
        (void*)&conv1_w, (void*)&conv1_b, (void*)&ln1_g, (void*)&ln1_b,
        (void*)&lin_w, (void*)&lin_b, (void*)&out,
        (void*)&spec, (void*)&bufA, (void*)&bufB,
        (void*)&wpre, (void*)&w0t, (void*)&w1t, (void*)&ends
    };
    hipError_t le = hipLaunchCooperativeKernel((const void*)mega_kernel, dim3(nblk),
                                               dim3(256), kargs, 0, stream);
    if (le == hipSuccess) return;
    (void)hipGetLastError();   // clear latched error before fallback

    // ---- fallback: proven 6-dispatch path ----
    wfrag_all_kernel<<<(36864 + 2 * 110592 + 255) / 256, 256, 0, stream>>>(
        pre_w, conv0_w, conv1_w, wpre, w0t, w1t);
    segmean_kernel<<<B * C_IN, 256, 0, stream>>>(x, w, spec);
    dim3 gt(N_PH / 32, (C_IN / 32) * B);
    transpose_spec_kernel<<<gt, 256, 0, stream>>>(spec, specT);
    dim3 gg(N_PH / 64, B);
    gemm_fused_kernel<<<gg, 256, 0, stream>>>(specT, N_PH, wpre, pre_b, x_mask,
                                              ln0_g, ln0_b, bufA,
                                              nullptr, nullptr, nullptr, 1, 0, 1, 0);
    gemm_fused_kernel<<<gg, 256, 0, stream>>>(bufA + ROWP, PROWS, w0t, conv0_b, x_mask,
                                              ln0_g, ln0_b, bufB,
                                              nullptr, nullptr, nullptr, 3, 1, 2, 0);
    gemm_fused_kernel<<<gg, 256, 0, stream>>>(bufB + ROWP, PROWS, w1t, conv1_b, x_mask,
                                              ln1_g, ln1_b, bufA,
                                              lin_w, lin_b, out, 3, 1, 1, 1);
}

// Round 5
// 401.757 us; speedup vs baseline: 2.0636x; 2.0636x over previous
//
#include <hip/hip_runtime.h>
#include <hip/hip_bf16.h>

#define B 32
#define C_IN 192
#define T 8192
#define H 192
#define N_PH 1024
#define OUT 4
#define PROWS (N_PH + 2)      // padded rows: t = -1 .. N_PH
#define ROWP (2 * H)          // row pitch: hi plane [0,H), lo plane [H,2H)

typedef __attribute__((ext_vector_type(8))) short short8;
typedef __attribute__((ext_vector_type(4))) float f32x4;
typedef unsigned short ushort_t;

__device__ inline ushort_t f2bf(float f) {
    unsigned u = __builtin_bit_cast(unsigned, f);
    unsigned r = u + 0x7fffu + ((u >> 16) & 1u);   // RNE
    return (ushort_t)(r >> 16);
}
__device__ inline float bf2f(ushort_t h) {
    unsigned u = ((unsigned)h) << 16;
    return __builtin_bit_cast(float, u);
}
// split x into hi+lo bf16 pair (~17-bit effective mantissa) -- accuracy-mandatory
__device__ inline void split_bf(float x, ushort_t& hi, ushort_t& lo) {
    hi = f2bf(x);
    lo = f2bf(x - bf2f(hi));
}

// ---------------- weight prep: MFMA-fragment-ordered, split hi/lo -----------
// Fragment slot (kt, s, nt): 512 ushort = lane*8 + j.
// Stored value: w[o = nt*16 + (lane&15)][k_in_tap = s*32 + (lane>>4)*8 + j][tap kt]
__device__ inline void wfrag_one(const float* __restrict__ w, ushort_t* __restrict__ wtf,
                                 int taps, int idx, int ntot) {
    int j  = idx & 7;
    int l  = (idx >> 3) & 63;
    int slot = idx >> 9;             // (kt*6 + s)*12 + nt
    int nt = slot % 12;
    int ss = (slot / 12) % 6;
    int kt = slot / 72;
    int o  = nt * 16 + (l & 15);
    int i  = ss * 32 + ((l >> 4) << 3) + j;
    float v = (taps == 1) ? w[o * C_IN + i] : w[(o * H + i) * 3 + kt];
    ushort_t hi, lo;
    split_bf(v, hi, lo);
    wtf[idx] = hi;
    wtf[idx + ntot] = lo;
}

// prep: weight fragments (blocks < NWF) + per-batch duration scan (blocks >= NWF)
#define NWF 1008   // ceil((36864 + 2*110592)/256)
__global__ __launch_bounds__(256) void prep_kernel(
    const float* __restrict__ pw, const float* __restrict__ w0,
    const float* __restrict__ w1, const int* __restrict__ wdur,
    ushort_t* __restrict__ wpre, ushort_t* __restrict__ w0t,
    ushort_t* __restrict__ w1t, int* __restrict__ ends)
{
    int blk = blockIdx.x;
    int tid = threadIdx.x;
    const int n1 = 36864, n3 = 110592;
    if (blk < NWF) {
        int idx = blk * 256 + tid;
        if (idx < n1) { wfrag_one(pw, wpre, 1, idx, n1); return; }
        idx -= n1;
        if (idx < n3) { wfrag_one(w0, w0t, 3, idx, n3); return; }
        idx -= n3;
        if (idx < n3) wfrag_one(w1, w1t, 3, idx, n3);
        return;
    }
    // inclusive scan of durations for batch b (1024 ints, 4/thread)
    int b = blk - NWF;
    __shared__ int part[256];
    int4 w4 = ((const int4*)(wdur + b * N_PH))[tid];
    int c0 = w4.x, c1 = c0 + w4.y, c2 = c1 + w4.z, c3 = c2 + w4.w;
    part[tid] = c3;
    __syncthreads();
    for (int off = 1; off < 256; off <<= 1) {
        int v = (tid >= off) ? part[tid - off] : 0;
        __syncthreads();
        part[tid] += v;
        __syncthreads();
    }
    int pre = tid ? part[tid - 1] : 0;
    int4 e4;
    e4.x = pre + c0; e4.y = pre + c1; e4.z = pre + c2; e4.w = pre + c3;
    ((int4*)(ends + b * N_PH))[tid] = e4;
}

// ---------------- segment mean, direct to time-major split-bf16 specT ----------------
// block = (b, 32-phoneme tile); threads = 8 channel-groups x 32 phonemes.
// Gathers x[b][c][s0..e0) straight from global (contiguous spans, L1/L2 friendly),
// stages the 32x192 result in LDS, then writes coalesced short8 rows.
__global__ __launch_bounds__(256) void segmean_direct_kernel(
    const float* __restrict__ x, const int* __restrict__ ends,
    ushort_t* __restrict__ specT)
{
    int b  = blockIdx.x >> 5;
    int jt = (blockIdx.x & 31) * 32;
    int tid = threadIdx.x;
    int j_loc = tid & 31;
    int cg0 = tid >> 5;            // 0..7
    int j = jt + j_loc;

    __shared__ float sm[32][193];

    const int* eb = ends + b * N_PH;
    int e0 = eb[j];
    int s0 = j ? eb[j - 1] : 0;
    int len = e0 - s0;
    float inv = (len > 0) ? 1.f / (float)len : 0.f;

    const float* xb = x + (size_t)b * C_IN * T;
#pragma unroll 1
    for (int c = cg0; c < C_IN; c += 8) {
        const float* xr = xb + (size_t)c * T;
        float sum = 0.f;
        for (int t = s0; t < e0; ++t) sum += xr[t];
        sm[j_loc][c] = sum * inv;
    }
    __syncthreads();

    // write rows: thread (r = tid>>3, g = tid&7) covers c in [g*24, g*24+24)
    int r = tid >> 3;
    int g = tid & 7;
    ushort_t* ob = specT + ((size_t)b * N_PH + jt + r) * ROWP;
#pragma unroll
    for (int i0 = 0; i0 < 24; i0 += 8) {
        ushort_t th[8], tl[8];
#pragma unroll
        for (int k2 = 0; k2 < 8; ++k2) {
            int c = g * 24 + i0 + k2;
            split_bf(sm[r][c], th[k2], tl[k2]);
        }
        *(short8*)(ob + g * 24 + i0) = *(short8*)th;
        *(short8*)(ob + H + g * 24 + i0) = *(short8*)tl;
    }
}

// ---------------- fused MFMA GEMM: conv(taps)+bias [+relu+LN] +mask [+final proj] ----
#define LOADOPS(IT, AH0, AL0, AH1, AL1, BH, BL) do {                              \
    int kt_ = (IT) / 6, s_ = (IT) - kt_ * 6;                                      \
    const ushort_t* arow_ = inb + (long)(trow + kt_ - pad) * ROWP + s_ * 32 + kg; \
    AH0 = *(const short8*)(arow_);                                                \
    AL0 = *(const short8*)(arow_ + H);                                            \
    AH1 = *(const short8*)(arow_ + 16 * ROWP);                                    \
    AL1 = *(const short8*)(arow_ + 16 * ROWP + H);                                \
    const ushort_t* wb_ = wt + ((size_t)((kt_ * 6 + s_) * 12 + nhalf * 6) << 9)   \
                        + (lane << 3);                                            \
    _Pragma("unroll") for (int n_ = 0; n_ < 6; ++n_) {                            \
        BH[n_] = *(const short8*)(wb_ + (n_ << 9));                               \
        BL[n_] = *(const short8*)(wb_ + (n_ << 9) + ntotw); }                     \
} while (0)

#define DOMFMA(AH0, AL0, AH1, AL1, BH, BL) do {                                             \
    _Pragma("unroll") for (int n_ = 0; n_ < 6; ++n_) {                                      \
        acc[0][n_] = __builtin_amdgcn_mfma_f32_16x16x32_bf16(AH0, BH[n_], acc[0][n_], 0,0,0); \
        acc[0][n_] = __builtin_amdgcn_mfma_f32_16x16x32_bf16(AL0, BH[n_], acc[0][n_], 0,0,0); \
        acc[0][n_] = __builtin_amdgcn_mfma_f32_16x16x32_bf16(AH0, BL[n_], acc[0][n_], 0,0,0); \
        acc[1][n_] = __builtin_amdgcn_mfma_f32_16x16x32_bf16(AH1, BH[n_], acc[1][n_], 0,0,0); \
        acc[1][n_] = __builtin_amdgcn_mfma_f32_16x16x32_bf16(AL1, BH[n_], acc[1][n_], 0,0,0); \
        acc[1][n_] = __builtin_amdgcn_mfma_f32_16x16x32_bf16(AH1, BL[n_], acc[1][n_], 0,0,0); } \
} while (0)

__global__ __launch_bounds__(256) void gemm_fused_kernel(
    const ushort_t* __restrict__ in, int in_rows,
    const ushort_t* __restrict__ wt,
    const float* __restrict__ bias,
    const float* __restrict__ mask,
    const float* __restrict__ g, const float* __restrict__ beta,
    ushort_t* __restrict__ out,
    const float* __restrict__ lw, const float* __restrict__ lb,
    float* __restrict__ fout,
    int taps, int do_ln, int nmask, int fin)
{
    int b  = blockIdx.y;
    int t0 = blockIdx.x * 64;
    int tid = threadIdx.x;
    int lane = tid & 63;
    int wv = tid >> 6;
    int mhalf = wv & 1;
    int nhalf = wv >> 1;

    __shared__ float ep[64][193];
    __shared__ float g_s[H], b_s[H], m_s[64], mstat[64], rstat[64];
    if (tid < H) { g_s[tid] = do_ln ? g[tid] : 1.f; b_s[tid] = do_ln ? beta[tid] : 0.f; }
    if (tid < 64) m_s[tid] = mask[b * N_PH + t0 + tid];

    // zero halo rows (t=-1 and t=N_PH), both planes (skip in fin mode: no store)
    short8 z8 = {0, 0, 0, 0, 0, 0, 0, 0};
    if (!fin) {
        if (t0 == 0 && tid < ROWP / 8)
            *(short8*)(out + (size_t)b * PROWS * ROWP + tid * 8) = z8;
        if (t0 == N_PH - 64 && tid < ROWP / 8)
            *(short8*)(out + ((size_t)b * PROWS + N_PH + 1) * ROWP + tid * 8) = z8;
    }

    int m  = lane & 15;                 // A time-row / B channel / D col
    int kg = (lane >> 4) << 3;          // k offset within 32-step: 0,8,16,24
    int ntotw = taps * 36864;           // hi-plane size; lo at +ntotw
    int pad = taps >> 1;

    const ushort_t* inb = in + (size_t)b * in_rows * ROWP;
    int trow = t0 + mhalf * 32 + m;     // +16 for second A-frag

    f32x4 acc[2][6];
#pragma unroll
    for (int ntl = 0; ntl < 6; ++ntl) {
        float bb = bias[(nhalf * 6 + ntl) * 16 + m];
        acc[0][ntl] = (f32x4){bb, bb, bb, bb};
        acc[1][ntl] = (f32x4){bb, bb, bb, bb};
    }

    // K-loop with register double-buffered prefetch (iters = 6 or 18, even)
    short8 pah0, pal0, pah1, pal1, pbh[6], pbl[6];
    short8 qah0, qal0, qah1, qal1, qbh[6], qbl[6];
    int iters = taps * 6;
    LOADOPS(0, pah0, pal0, pah1, pal1, pbh, pbl);
#pragma unroll 1
    for (int it = 0; it < iters; it += 2) {
        LOADOPS(it + 1, qah0, qal0, qah1, qal1, qbh, qbl);
        DOMFMA(pah0, pal0, pah1, pal1, pbh, pbl);
        if (it + 2 < iters) LOADOPS(it + 2, pah0, pal0, pah1, pal1, pbh, pbl);
        DOMFMA(qah0, qal0, qah1, qal1, qbh, qbl);
    }

    __syncthreads();   // covers g_s/b_s/m_s staging

    // write pre-LN (or final-masked) values to LDS, C/D layout -> [time][channel]
    int rbase = (lane >> 4) << 2;
#pragma unroll
    for (int mh = 0; mh < 2; ++mh) {
#pragma unroll
        for (int ntl = 0; ntl < 6; ++ntl) {
            int o = (nhalf * 6 + ntl) * 16 + m;
#pragma unroll
            for (int r = 0; r < 4; ++r) {
                int t_loc = mhalf * 32 + mh * 16 + rbase + r;
                float mm = m_s[t_loc];
                float v = acc[mh][ntl][r];
                if (do_ln) {
                    v = fmaxf(v * mm, 0.f) * mm;     // relu(conv*mask)*mask -> LN input
                } else {
                    for (int q = 0; q < nmask; ++q) v *= mm;
                }
                ep[t_loc][o] = v;
            }
        }
    }
    __syncthreads();

    // LN stats: one thread per time row
    if (do_ln && tid < 64) {
        float s = 0.f, ss = 0.f;
        for (int c = 0; c < H; ++c) {
            float v = ep[tid][c];
            s += v;
            ss += v * v;
        }
        float mean = s * (1.f / (float)H);
        mstat[tid] = mean;
        rstat[tid] = rsqrtf(ss * (1.f / (float)H) - mean * mean + 1e-5f);
    }
    __syncthreads();

    int row = tid >> 2;
    int q = tid & 3;
    if (fin) {
        // fused final projection: p[o] = (sum_c lw[o][c] * (ln(c)*mk) + lb[o]) * mk
        float mean = mstat[row], rstd = rstat[row], mk = m_s[row];
        float a0 = 0.f, a1 = 0.f, a2 = 0.f, a3 = 0.f;
#pragma unroll 1
        for (int c = q * 48; c < q * 48 + 48; ++c) {
            float y = ((ep[row][c] - mean) * rstd * g_s[c] + b_s[c]) * mk;
            a0 += lw[0 * H + c] * y;
            a1 += lw[1 * H + c] * y;
            a2 += lw[2 * H + c] * y;
            a3 += lw[3 * H + c] * y;
        }
        a0 += __shfl_xor(a0, 1); a0 += __shfl_xor(a0, 2);
        a1 += __shfl_xor(a1, 1); a1 += __shfl_xor(a1, 2);
        a2 += __shfl_xor(a2, 1); a2 += __shfl_xor(a2, 2);
        a3 += __shfl_xor(a3, 1); a3 += __shfl_xor(a3, 2);
        if (q == 0) {
            int t = t0 + row;
            float* ob = fout + (size_t)b * OUT * N_PH + t;
            ob[0 * N_PH] = (a0 + lb[0]) * mk;
            ob[1 * N_PH] = (a1 + lb[1]) * mk;
            ob[2 * N_PH] = (a2 + lb[2]) * mk;
            ob[3 * N_PH] = (a3 + lb[3]) * mk;
        }
        return;
    }

    // store: 4 threads per row, 48 channels each, split bf16
    float mean = 0.f, rstd = 1.f, mfac = 1.f;
    if (do_ln) {
        mean = mstat[row];
        rstd = rstat[row];
        float mk = m_s[row];
        mfac = (nmask == 2) ? mk * mk : mk;
    }
    ushort_t* orow = out + ((size_t)b * PROWS + t0 + row + 1) * ROWP + q * 48;
#pragma unroll
    for (int i0 = 0; i0 < 48; i0 += 8) {
        ushort_t th[8], tl[8];
#pragma unroll
        for (int k2 = 0; k2 < 8; ++k2) {
            int c = q * 48 + i0 + k2;
            float v = ep[row][c];
            float y = do_ln ? ((v - mean) * rstd * g_s[c] + b_s[c]) * mfac : v;
            split_bf(y, th[k2], tl[k2]);
        }
        *(short8*)(orow + i0) = *(short8*)th;
        *(short8*)(orow + H + i0) = *(short8*)tl;
    }
}

extern "C" void kernel_launch(void* const* d_in, const int* in_sizes, int n_in,
                              void* d_out, int out_size, void* d_ws, size_t ws_size,
                              hipStream_t stream) {
    const float* x      = (const float*)d_in[0];
    const float* x_mask = (const float*)d_in[1];
    const int*   w      = (const int*)d_in[2];
    const float* pre_w  = (const float*)d_in[3];
    const float* pre_b  = (const float*)d_in[4];
    const float* conv0_w = (const float*)d_in[5];
    const float* conv0_b = (const float*)d_in[6];
    const float* ln0_g   = (const float*)d_in[7];
    const float* ln0_b   = (const float*)d_in[8];
    const float* conv1_w = (const float*)d_in[9];
    const float* conv1_b = (const float*)d_in[10];
    const float* ln1_g   = (const float*)d_in[11];
    const float* ln1_b   = (const float*)d_in[12];
    const float* lin_w   = (const float*)d_in[13];
    const float* lin_b   = (const float*)d_in[14];
    float* out = (float*)d_out;

    // workspace layout
    char* ws = (char*)d_ws;
    size_t off = 0;
    ushort_t* bufA = (ushort_t*)(ws + off); off += (size_t)B * PROWS * ROWP * sizeof(ushort_t);
    ushort_t* bufB = (ushort_t*)(ws + off); off += (size_t)B * PROWS * ROWP * sizeof(ushort_t);
    ushort_t* wpre = (ushort_t*)(ws + off); off += (size_t)2 * 36864 * sizeof(ushort_t);
    ushort_t* w0t  = (ushort_t*)(ws + off); off += (size_t)2 * 110592 * sizeof(ushort_t);
    ushort_t* w1t  = (ushort_t*)(ws + off); off += (size_t)2 * 110592 * sizeof(ushort_t);
    int* ends      = (int*)(ws + off);      off += (size_t)B * N_PH * sizeof(int);
    // specT aliases bufB: consumed by pre-GEMM before conv0 first writes bufB
    ushort_t* specT = bufB;

    // weight fragments + per-batch duration scans, one dispatch
    prep_kernel<<<NWF + B, 256, 0, stream>>>(pre_w, conv0_w, conv1_w, w,
                                             wpre, w0t, w1t, ends);

    // segment mean -> time-major split bf16 (direct, no fp32 round-trip)
    segmean_direct_kernel<<<B * 32, 256, 0, stream>>>(x, ends, specT);

    dim3 gg(N_PH / 64, B);
    // pre linear: specT (pitch N_PH rows) -> bufA (mask applied for conv0 input)
    gemm_fused_kernel<<<gg, 256, 0, stream>>>(specT, N_PH, wpre, pre_b, x_mask,
                                              ln0_g, ln0_b, bufA,
                                              nullptr, nullptr, nullptr, 1, 0, 1, 0);
    // block 0: bufA -> bufB  (out = ln0*mask, + conv1's leading mask)
    gemm_fused_kernel<<<gg, 256, 0, stream>>>(bufA + ROWP, PROWS, w0t, conv0_b, x_mask,
                                              ln0_g, ln0_b, bufB,
                                              nullptr, nullptr, nullptr, 3, 1, 2, 0);
    // block 1 + fused final projection: bufB -> out
    gemm_fused_kernel<<<gg, 256, 0, stream>>>(bufB + ROWP, PROWS, w1t, conv1_b, x_mask,
                                              ln1_g, ln1_b, bufA,
                                              lin_w, lin_b, out, 3, 1, 1, 1);
}

// Round 6
// 376.555 us; speedup vs baseline: 2.2017x; 1.0669x over previous
//
#include <hip/hip_runtime.h>
#include <hip/hip_bf16.h>

#define B 32
#define C_IN 192
#define T 8192
#define H 192
#define N_PH 1024
#define OUT 4
#define ROWP (2 * H)          // specT row pitch: hi plane [0,H), lo plane [H,2H)
#define HPITCH 392            // hbuf row pitch (ushort): 784B = 16B-aligned, 4-bank row shift

typedef __attribute__((ext_vector_type(8))) short short8;
typedef __attribute__((ext_vector_type(4))) float f32x4;
typedef unsigned short ushort_t;

__device__ inline ushort_t f2bf(float f) {
    unsigned u = __builtin_bit_cast(unsigned, f);
    unsigned r = u + 0x7fffu + ((u >> 16) & 1u);   // RNE
    return (ushort_t)(r >> 16);
}
__device__ inline float bf2f(ushort_t h) {
    unsigned u = ((unsigned)h) << 16;
    return __builtin_bit_cast(float, u);
}
// split x into hi+lo bf16 pair (~17-bit effective mantissa) -- accuracy-mandatory
__device__ inline void split_bf(float x, ushort_t& hi, ushort_t& lo) {
    hi = f2bf(x);
    lo = f2bf(x - bf2f(hi));
}

// ---------------- weight prep: MFMA-fragment-ordered, split hi/lo -----------
// Fragment slot (kt, s, nt): 512 ushort = lane*8 + j.
// Stored value: w[o = nt*16 + (lane&15)][k_in_tap = s*32 + (lane>>4)*8 + j][tap kt]
__device__ inline void wfrag_one(const float* __restrict__ w, ushort_t* __restrict__ wtf,
                                 int taps, int idx, int ntot) {
    int j  = idx & 7;
    int l  = (idx >> 3) & 63;
    int slot = idx >> 9;             // (kt*6 + s)*12 + nt
    int nt = slot % 12;
    int ss = (slot / 12) % 6;
    int kt = slot / 72;
    int o  = nt * 16 + (l & 15);
    int i  = ss * 32 + ((l >> 4) << 3) + j;
    float v = (taps == 1) ? w[o * C_IN + i] : w[(o * H + i) * 3 + kt];
    ushort_t hi, lo;
    split_bf(v, hi, lo);
    wtf[idx] = hi;
    wtf[idx + ntot] = lo;
}

// prep: weight fragments (blocks < NWF) + per-batch duration scan (blocks >= NWF)
#define NWF 1008   // ceil((36864 + 2*110592)/256)
__global__ __launch_bounds__(256) void prep_kernel(
    const float* __restrict__ pw, const float* __restrict__ w0,
    const float* __restrict__ w1, const int* __restrict__ wdur,
    ushort_t* __restrict__ wpre, ushort_t* __restrict__ w0t,
    ushort_t* __restrict__ w1t, int* __restrict__ ends)
{
    int blk = blockIdx.x;
    int tid = threadIdx.x;
    const int n1 = 36864, n3 = 110592;
    if (blk < NWF) {
        int idx = blk * 256 + tid;
        if (idx < n1) { wfrag_one(pw, wpre, 1, idx, n1); return; }
        idx -= n1;
        if (idx < n3) { wfrag_one(w0, w0t, 3, idx, n3); return; }
        idx -= n3;
        if (idx < n3) wfrag_one(w1, w1t, 3, idx, n3);
        return;
    }
    // inclusive scan of durations for batch b (1024 ints, 4/thread)
    int b = blk - NWF;
    __shared__ int part[256];
    int4 w4 = ((const int4*)(wdur + b * N_PH))[tid];
    int c0 = w4.x, c1 = c0 + w4.y, c2 = c1 + w4.z, c3 = c2 + w4.w;
    part[tid] = c3;
    __syncthreads();
    for (int off = 1; off < 256; off <<= 1) {
        int v = (tid >= off) ? part[tid - off] : 0;
        __syncthreads();
        part[tid] += v;
        __syncthreads();
    }
    int pre = tid ? part[tid - 1] : 0;
    int4 e4;
    e4.x = pre + c0; e4.y = pre + c1; e4.z = pre + c2; e4.w = pre + c3;
    ((int4*)(ends + b * N_PH))[tid] = e4;
}

// ---------------- segment mean, direct to time-major split-bf16 specT ----------------
__global__ __launch_bounds__(256) void segmean_direct_kernel(
    const float* __restrict__ x, const int* __restrict__ ends,
    ushort_t* __restrict__ specT)
{
    int b  = blockIdx.x >> 5;
    int jt = (blockIdx.x & 31) * 32;
    int tid = threadIdx.x;
    int j_loc = tid & 31;
    int cg0 = tid >> 5;            // 0..7
    int j = jt + j_loc;

    __shared__ float sm[32][193];

    const int* eb = ends + b * N_PH;
    int e0 = eb[j];
    int s0 = j ? eb[j - 1] : 0;
    int len = e0 - s0;
    float inv = (len > 0) ? 1.f / (float)len : 0.f;

    const float* xb = x + (size_t)b * C_IN * T;
#pragma unroll 1
    for (int c = cg0; c < C_IN; c += 8) {
        const float* xr = xb + (size_t)c * T;
        float sum = 0.f;
        for (int t = s0; t < e0; ++t) sum += xr[t];
        sm[j_loc][c] = sum * inv;
    }
    __syncthreads();

    // write rows: thread (r = tid>>3, g = tid&7) covers c in [g*24, g*24+24)
    int r = tid >> 3;
    int g = tid & 7;
    ushort_t* ob = specT + ((size_t)b * N_PH + jt + r) * ROWP;
#pragma unroll
    for (int i0 = 0; i0 < 24; i0 += 8) {
        ushort_t th[8], tl[8];
#pragma unroll
        for (int k2 = 0; k2 < 8; ++k2) {
            int c = g * 24 + i0 + k2;
            split_bf(sm[r][c], th[k2], tl[k2]);
        }
        *(short8*)(ob + g * 24 + i0) = *(short8*)th;
        *(short8*)(ob + H + g * 24 + i0) = *(short8*)tl;
    }
}

// ---------------- fused chain: pre-linear + conv0+LN0 + conv1+LN1 + projection ----
// One block = 64 output rows (t0..t0+63) of one batch. Halo recompute; h0/h1/w live
// in a single LDS region sequentially. m_s==0 outside [0,N_PH) makes every masked
// store implement the reference's zero conv padding automatically.
__global__ __launch_bounds__(256) void chain_kernel(
    const ushort_t* __restrict__ specT,
    const ushort_t* __restrict__ wpre, const ushort_t* __restrict__ w0t,
    const ushort_t* __restrict__ w1t,
    const float* __restrict__ pre_b, const float* __restrict__ c0_b,
    const float* __restrict__ c1_b,
    const float* __restrict__ mask,
    const float* __restrict__ g0, const float* __restrict__ be0,
    const float* __restrict__ g1, const float* __restrict__ be1,
    const float* __restrict__ lw, const float* __restrict__ lb,
    float* __restrict__ out)
{
    const int b  = blockIdx.y;
    const int t0 = blockIdx.x * 64;
    const int tid = threadIdx.x;
    const int lane = tid & 63;
    const int wv = tid >> 6;
    const int nhalf = wv >> 1;          // B/N half: cols nhalf*96..+95
    const int mgrp = wv & 1;            // M-frag group
    const int m = lane & 15;
    const int kg = (lane >> 4) << 3;
    const int rbase = (lane >> 4) << 2;

    __shared__ ushort_t hbuf[82 * HPITCH];          // h0 (82 rows) -> h1 (66) -> w (64)
    __shared__ float g0_s[H], b0_s[H], g1_s[H], b1_s[H];
    __shared__ float lw_s[OUT * H];
    __shared__ float m_s[96], mstat[66], rstat[66];

    if (tid < H) { g0_s[tid] = g0[tid]; b0_s[tid] = be0[tid];
                   g1_s[tid] = g1[tid]; b1_s[tid] = be1[tid]; }
    if (tid < 96) {
        int grow = t0 - 2 + tid;
        m_s[tid] = (grow >= 0 && grow < N_PH) ? mask[b * N_PH + grow] : 0.f;
    }
    for (int i = tid; i < OUT * H; i += 256) lw_s[i] = lw[i];
    __syncthreads();   // m_s / params visible to all

    const short8 z8 = {0, 0, 0, 0, 0, 0, 0, 0};

    // ================= stage P: pre-linear (taps=1, K=192), M=96, keep 82 rows ======
    {
        f32x4 acc[3][6];
#pragma unroll
        for (int n = 0; n < 6; ++n) {
            float bb = pre_b[(nhalf * 6 + n) * 16 + m];
#pragma unroll
            for (int f = 0; f < 3; ++f) acc[f][n] = (f32x4){bb, bb, bb, bb};
        }
        const ushort_t* inb = specT + (size_t)b * N_PH * ROWP;
#pragma unroll 1
        for (int s = 0; s < 6; ++s) {
            short8 ah[3], al[3], bh[6], bl[6];
#pragma unroll
            for (int f = 0; f < 3; ++f) {
                int trow = t0 - 2 + (mgrp * 3 + f) * 16 + m;
                if ((unsigned)trow < (unsigned)N_PH) {
                    const ushort_t* ar = inb + (size_t)trow * ROWP + s * 32 + kg;
                    ah[f] = *(const short8*)ar;
                    al[f] = *(const short8*)(ar + H);
                } else { ah[f] = z8; al[f] = z8; }
            }
            const ushort_t* wb = wpre + ((size_t)(s * 12 + nhalf * 6) << 9) + (lane << 3);
#pragma unroll
            for (int n = 0; n < 6; ++n) {
                bh[n] = *(const short8*)(wb + (n << 9));
                bl[n] = *(const short8*)(wb + (n << 9) + 36864);
            }
#pragma unroll
            for (int f = 0; f < 3; ++f)
#pragma unroll
                for (int n = 0; n < 6; ++n) {
                    acc[f][n] = __builtin_amdgcn_mfma_f32_16x16x32_bf16(ah[f], bh[n], acc[f][n], 0, 0, 0);
                    acc[f][n] = __builtin_amdgcn_mfma_f32_16x16x32_bf16(al[f], bh[n], acc[f][n], 0, 0, 0);
                    acc[f][n] = __builtin_amdgcn_mfma_f32_16x16x32_bf16(ah[f], bl[n], acc[f][n], 0, 0, 0);
                }
        }
        // store h0 = pre_out * mask (mask=0 pads OOR rows to zero)
#pragma unroll
        for (int f = 0; f < 3; ++f) {
            int lb0 = (mgrp * 3 + f) * 16 + rbase;
#pragma unroll
            for (int n = 0; n < 6; ++n) {
                int col = (nhalf * 6 + n) * 16 + m;
#pragma unroll
                for (int r = 0; r < 4; ++r) {
                    int l = lb0 + r;
                    if (l < 82) {
                        float v = acc[f][n][r] * m_s[l];
                        ushort_t hi, lo; split_bf(v, hi, lo);
                        hbuf[l * HPITCH + col] = hi;
                        hbuf[l * HPITCH + H + col] = lo;
                    }
                }
            }
        }
    }
    __syncthreads();

    // ================= stage C0: conv0 (taps=3), frags mgrp0:{0,1,2} mgrp1:{3,4} ====
    {
        f32x4 acc[3][6];
        const int nf = mgrp ? 2 : 3;
        const int fbase = mgrp * 3;
#pragma unroll
        for (int n = 0; n < 6; ++n) {
            float bb = c0_b[(nhalf * 6 + n) * 16 + m];
#pragma unroll
            for (int f = 0; f < 3; ++f) acc[f][n] = (f32x4){bb, bb, bb, bb};
        }
#pragma unroll 1
        for (int kt = 0; kt < 3; ++kt)
#pragma unroll 1
            for (int s = 0; s < 6; ++s) {
                short8 ah[3], al[3], bh[6], bl[6];
#pragma unroll
                for (int f = 0; f < 3; ++f) {
                    if (f < nf) {
                        int l0 = (fbase + f) * 16 + m + kt;      // in [0,82)
                        const ushort_t* ar = hbuf + l0 * HPITCH + s * 32 + kg;
                        ah[f] = *(const short8*)ar;
                        al[f] = *(const short8*)(ar + H);
                    }
                }
                const ushort_t* wb = w0t + ((size_t)((kt * 6 + s) * 12 + nhalf * 6) << 9) + (lane << 3);
#pragma unroll
                for (int n = 0; n < 6; ++n) {
                    bh[n] = *(const short8*)(wb + (n << 9));
                    bl[n] = *(const short8*)(wb + (n << 9) + 110592);
                }
#pragma unroll
                for (int f = 0; f < 3; ++f) {
                    if (f < nf) {
#pragma unroll
                        for (int n = 0; n < 6; ++n) {
                            acc[f][n] = __builtin_amdgcn_mfma_f32_16x16x32_bf16(ah[f], bh[n], acc[f][n], 0, 0, 0);
                            acc[f][n] = __builtin_amdgcn_mfma_f32_16x16x32_bf16(al[f], bh[n], acc[f][n], 0, 0, 0);
                            acc[f][n] = __builtin_amdgcn_mfma_f32_16x16x32_bf16(ah[f], bl[n], acc[f][n], 0, 0, 0);
                        }
                    }
                }
            }
        __syncthreads();   // all h0 reads complete before overwrite
        // store u = relu(v*m)*m into rows 0..65 (h1 region, overwrites h0)
#pragma unroll
        for (int f = 0; f < 3; ++f) {
            if (f < nf) {
                int lb1 = (fbase + f) * 16 + rbase;
#pragma unroll
                for (int n = 0; n < 6; ++n) {
                    int col = (nhalf * 6 + n) * 16 + m;
#pragma unroll
                    for (int r = 0; r < 4; ++r) {
                        int l = lb1 + r;
                        if (l < 66) {
                            float mm = m_s[l + 1];
                            float u = fmaxf(acc[f][n][r] * mm, 0.f) * mm;
                            ushort_t hi, lo; split_bf(u, hi, lo);
                            hbuf[l * HPITCH + col] = hi;
                            hbuf[l * HPITCH + H + col] = lo;
                        }
                    }
                }
            }
        }
    }
    __syncthreads();

    // LN0 stats (per time row, over channels)
    if (tid < 66) {
        float s = 0.f, ss = 0.f;
        for (int c = 0; c < H; ++c) {
            float v = bf2f(hbuf[tid * HPITCH + c]) + bf2f(hbuf[tid * HPITCH + H + c]);
            s += v; ss += v * v;
        }
        float mean = s * (1.f / (float)H);
        mstat[tid] = mean;
        rstat[tid] = rsqrtf(ss * (1.f / (float)H) - mean * mean + 1e-5f);
    }
    __syncthreads();
    // LN0 apply in place, * mask^2 (LN-out mask + conv1 leading mask)
    for (int idx = tid; idx < 66 * H; idx += 256) {
        int row = idx / H;
        int c = idx - row * H;
        float v = bf2f(hbuf[row * HPITCH + c]) + bf2f(hbuf[row * HPITCH + H + c]);
        float mm = m_s[row + 1];
        float y = ((v - mstat[row]) * rstat[row] * g0_s[c] + b0_s[c]) * (mm * mm);
        ushort_t hi, lo; split_bf(y, hi, lo);
        hbuf[row * HPITCH + c] = hi;
        hbuf[row * HPITCH + H + c] = lo;
    }
    __syncthreads();

    // ================= stage C1: conv1 (taps=3), frags mgrp0:{0,1} mgrp1:{2,3} ======
    {
        f32x4 acc[2][6];
#pragma unroll
        for (int n = 0; n < 6; ++n) {
            float bb = c1_b[(nhalf * 6 + n) * 16 + m];
            acc[0][n] = (f32x4){bb, bb, bb, bb};
            acc[1][n] = (f32x4){bb, bb, bb, bb};
        }
#pragma unroll 1
        for (int kt = 0; kt < 3; ++kt)
#pragma unroll 1
            for (int s = 0; s < 6; ++s) {
                short8 ah[2], al[2], bh[6], bl[6];
#pragma unroll
                for (int f = 0; f < 2; ++f) {
                    int l1 = (mgrp * 2 + f) * 16 + m + kt;       // in [0,66)
                    const ushort_t* ar = hbuf + l1 * HPITCH + s * 32 + kg;
                    ah[f] = *(const short8*)ar;
                    al[f] = *(const short8*)(ar + H);
                }
                const ushort_t* wb = w1t + ((size_t)((kt * 6 + s) * 12 + nhalf * 6) << 9) + (lane << 3);
#pragma unroll
                for (int n = 0; n < 6; ++n) {
                    bh[n] = *(const short8*)(wb + (n << 9));
                    bl[n] = *(const short8*)(wb + (n << 9) + 110592);
                }
#pragma unroll
                for (int f = 0; f < 2; ++f)
#pragma unroll
                    for (int n = 0; n < 6; ++n) {
                        acc[f][n] = __builtin_amdgcn_mfma_f32_16x16x32_bf16(ah[f], bh[n], acc[f][n], 0, 0, 0);
                        acc[f][n] = __builtin_amdgcn_mfma_f32_16x16x32_bf16(al[f], bh[n], acc[f][n], 0, 0, 0);
                        acc[f][n] = __builtin_amdgcn_mfma_f32_16x16x32_bf16(ah[f], bl[n], acc[f][n], 0, 0, 0);
                    }
            }
        __syncthreads();   // all h1 reads complete before overwrite
        // store w = relu(v*m)*m into rows 0..63
#pragma unroll
        for (int f = 0; f < 2; ++f) {
            int lb2 = (mgrp * 2 + f) * 16 + rbase;
#pragma unroll
            for (int n = 0; n < 6; ++n) {
                int col = (nhalf * 6 + n) * 16 + m;
#pragma unroll
                for (int r = 0; r < 4; ++r) {
                    int l = lb2 + r;                              // < 64 always
                    float mm = m_s[l + 2];
                    float u = fmaxf(acc[f][n][r] * mm, 0.f) * mm;
                    ushort_t hi, lo; split_bf(u, hi, lo);
                    hbuf[l * HPITCH + col] = hi;
                    hbuf[l * HPITCH + H + col] = lo;
                }
            }
        }
    }
    __syncthreads();

    // LN1 stats
    if (tid < 64) {
        float s = 0.f, ss = 0.f;
        for (int c = 0; c < H; ++c) {
            float v = bf2f(hbuf[tid * HPITCH + c]) + bf2f(hbuf[tid * HPITCH + H + c]);
            s += v; ss += v * v;
        }
        float mean = s * (1.f / (float)H);
        mstat[tid] = mean;
        rstat[tid] = rsqrtf(ss * (1.f / (float)H) - mean * mean + 1e-5f);
    }
    __syncthreads();

    // fused final projection: p[o] = (sum_c lw[o][c] * (ln1(c)*mk) + lb[o]) * mk
    {
        int row = tid >> 2;
        int q = tid & 3;
        float mean = mstat[row], rstd = rstat[row], mk = m_s[row + 2];
        float a0 = 0.f, a1 = 0.f, a2 = 0.f, a3 = 0.f;
#pragma unroll 1
        for (int c = q * 48; c < q * 48 + 48; ++c) {
            float v = bf2f(hbuf[row * HPITCH + c]) + bf2f(hbuf[row * HPITCH + H + c]);
            float y = ((v - mean) * rstd * g1_s[c] + b1_s[c]) * mk;
            a0 += lw_s[0 * H + c] * y;
            a1 += lw_s[1 * H + c] * y;
            a2 += lw_s[2 * H + c] * y;
            a3 += lw_s[3 * H + c] * y;
        }
        a0 += __shfl_xor(a0, 1); a0 += __shfl_xor(a0, 2);
        a1 += __shfl_xor(a1, 1); a1 += __shfl_xor(a1, 2);
        a2 += __shfl_xor(a2, 1); a2 += __shfl_xor(a2, 2);
        a3 += __shfl_xor(a3, 1); a3 += __shfl_xor(a3, 2);
        if (q == 0) {
            int t = t0 + row;
            float* ob = out + (size_t)b * OUT * N_PH + t;
            ob[0 * N_PH] = (a0 + lb[0]) * mk;
            ob[1 * N_PH] = (a1 + lb[1]) * mk;
            ob[2 * N_PH] = (a2 + lb[2]) * mk;
            ob[3 * N_PH] = (a3 + lb[3]) * mk;
        }
    }
}

extern "C" void kernel_launch(void* const* d_in, const int* in_sizes, int n_in,
                              void* d_out, int out_size, void* d_ws, size_t ws_size,
                              hipStream_t stream) {
    const float* x      = (const float*)d_in[0];
    const float* x_mask = (const float*)d_in[1];
    const int*   w      = (const int*)d_in[2];
    const float* pre_w  = (const float*)d_in[3];
    const float* pre_b  = (const float*)d_in[4];
    const float* conv0_w = (const float*)d_in[5];
    const float* conv0_b = (const float*)d_in[6];
    const float* ln0_g   = (const float*)d_in[7];
    const float* ln0_b   = (const float*)d_in[8];
    const float* conv1_w = (const float*)d_in[9];
    const float* conv1_b = (const float*)d_in[10];
    const float* ln1_g   = (const float*)d_in[11];
    const float* ln1_b   = (const float*)d_in[12];
    const float* lin_w   = (const float*)d_in[13];
    const float* lin_b   = (const float*)d_in[14];
    float* out = (float*)d_out;

    // workspace layout
    char* ws = (char*)d_ws;
    size_t off = 0;
    ushort_t* specT = (ushort_t*)(ws + off); off += (size_t)B * N_PH * ROWP * sizeof(ushort_t);
    ushort_t* wpre  = (ushort_t*)(ws + off); off += (size_t)2 * 36864 * sizeof(ushort_t);
    ushort_t* w0t   = (ushort_t*)(ws + off); off += (size_t)2 * 110592 * sizeof(ushort_t);
    ushort_t* w1t   = (ushort_t*)(ws + off); off += (size_t)2 * 110592 * sizeof(ushort_t);
    int* ends       = (int*)(ws + off);      off += (size_t)B * N_PH * sizeof(int);

    // weight fragments + per-batch duration scans, one dispatch
    prep_kernel<<<NWF + B, 256, 0, stream>>>(pre_w, conv0_w, conv1_w, w,
                                             wpre, w0t, w1t, ends);

    // segment mean -> time-major split bf16
    segmean_direct_kernel<<<B * 32, 256, 0, stream>>>(x, ends, specT);

    // whole post-segmean chain, one dispatch, independent 64-row tiles
    chain_kernel<<<dim3(N_PH / 64, B), 256, 0, stream>>>(
        specT, wpre, w0t, w1t, pre_b, conv0_b, conv1_b, x_mask,
        ln0_g, ln0_b, ln1_g, ln1_b, lin_w, lin_b, out);
}

// Round 12
// 376.501 us; speedup vs baseline: 2.2020x; 1.0001x over previous
//
#include <hip/hip_runtime.h>
#include <hip/hip_bf16.h>

#define B 32
#define C_IN 192
#define T 8192
#define H 192
#define N_PH 1024
#define OUT 4
#define ROWP (2 * H)          // specT row pitch: hi plane [0,H), lo plane [H,2H)
#define HPITCH 392            // hbuf row pitch (ushort): 784B, 16B-aligned
#define TILE 32               // output rows per chain block

typedef __attribute__((ext_vector_type(8))) short short8;
typedef __attribute__((ext_vector_type(4))) float f32x4;
typedef unsigned short ushort_t;

__device__ inline ushort_t f2bf(float f) {
    unsigned u = __builtin_bit_cast(unsigned, f);
    unsigned r = u + 0x7fffu + ((u >> 16) & 1u);   // RNE
    return (ushort_t)(r >> 16);
}
__device__ inline float bf2f(ushort_t h) {
    unsigned u = ((unsigned)h) << 16;
    return __builtin_bit_cast(float, u);
}
// split x into hi+lo bf16 pair (~17-bit effective mantissa) -- accuracy-mandatory
__device__ inline void split_bf(float x, ushort_t& hi, ushort_t& lo) {
    hi = f2bf(x);
    lo = f2bf(x - bf2f(hi));
}

// ---------------- weight prep: MFMA-fragment-ordered, split hi/lo -----------
__device__ inline void wfrag_one(const float* __restrict__ w, ushort_t* __restrict__ wtf,
                                 int taps, int idx, int ntot) {
    int j  = idx & 7;
    int l  = (idx >> 3) & 63;
    int slot = idx >> 9;             // (kt*6 + s)*12 + nt
    int nt = slot % 12;
    int ss = (slot / 12) % 6;
    int kt = slot / 72;
    int o  = nt * 16 + (l & 15);
    int i  = ss * 32 + ((l >> 4) << 3) + j;
    float v = (taps == 1) ? w[o * C_IN + i] : w[(o * H + i) * 3 + kt];
    ushort_t hi, lo;
    split_bf(v, hi, lo);
    wtf[idx] = hi;
    wtf[idx + ntot] = lo;
}

#define NWF 1008   // ceil((36864 + 2*110592)/256)
__global__ __launch_bounds__(256) void prep_kernel(
    const float* __restrict__ pw, const float* __restrict__ w0,
    const float* __restrict__ w1, const int* __restrict__ wdur,
    ushort_t* __restrict__ wpre, ushort_t* __restrict__ w0t,
    ushort_t* __restrict__ w1t, int* __restrict__ ends)
{
    int blk = blockIdx.x;
    int tid = threadIdx.x;
    const int n1 = 36864, n3 = 110592;
    if (blk < NWF) {
        int idx = blk * 256 + tid;
        if (idx < n1) { wfrag_one(pw, wpre, 1, idx, n1); return; }
        idx -= n1;
        if (idx < n3) { wfrag_one(w0, w0t, 3, idx, n3); return; }
        idx -= n3;
        if (idx < n3) wfrag_one(w1, w1t, 3, idx, n3);
        return;
    }
    int b = blk - NWF;
    __shared__ int part[256];
    int4 w4 = ((const int4*)(wdur + b * N_PH))[tid];
    int c0 = w4.x, c1 = c0 + w4.y, c2 = c1 + w4.z, c3 = c2 + w4.w;
    part[tid] = c3;
    __syncthreads();
    for (int off = 1; off < 256; off <<= 1) {
        int v = (tid >= off) ? part[tid - off] : 0;
        __syncthreads();
        part[tid] += v;
        __syncthreads();
    }
    int pre = tid ? part[tid - 1] : 0;
    int4 e4;
    e4.x = pre + c0; e4.y = pre + c1; e4.z = pre + c2; e4.w = pre + c3;
    ((int4*)(ends + b * N_PH))[tid] = e4;
}

// ---------------- segment mean, direct to time-major split-bf16 specT ----------------
__global__ __launch_bounds__(256) void segmean_direct_kernel(
    const float* __restrict__ x, const int* __restrict__ ends,
    ushort_t* __restrict__ specT)
{
    int b  = blockIdx.x >> 5;
    int jt = (blockIdx.x & 31) * 32;
    int tid = threadIdx.x;
    int j_loc = tid & 31;
    int cg0 = tid >> 5;            // 0..7
    int j = jt + j_loc;

    __shared__ float sm[32][193];

    const int* eb = ends + b * N_PH;
    int e0 = eb[j];
    int s0 = j ? eb[j - 1] : 0;
    int len = e0 - s0;
    float inv = (len > 0) ? 1.f / (float)len : 0.f;

    const float* xb = x + (size_t)b * C_IN * T;
#pragma unroll 1
    for (int c = cg0; c < C_IN; c += 8) {
        const float* xr = xb + (size_t)c * T;
        float sum = 0.f;
        for (int t = s0; t < e0; ++t) sum += xr[t];
        sm[j_loc][c] = sum * inv;
    }
    __syncthreads();

    int r = tid >> 3;
    int g = tid & 7;
    ushort_t* ob = specT + ((size_t)b * N_PH + jt + r) * ROWP;
#pragma unroll
    for (int i0 = 0; i0 < 24; i0 += 8) {
        ushort_t th[8], tl[8];
#pragma unroll
        for (int k2 = 0; k2 < 8; ++k2) {
            int c = g * 24 + i0 + k2;
            split_bf(sm[r][c], th[k2], tl[k2]);
        }
        *(short8*)(ob + g * 24 + i0) = *(short8*)th;
        *(short8*)(ob + H + g * 24 + i0) = *(short8*)tl;
    }
}

// ---------------- fused chain, TILE=32: pre + conv0+LN0 + conv1+LN1 + proj ----
// One block = 32 output rows. hbuf rows (local l):
//   h0: l=0..35  <-> pre-linear rows t0-2+l   (P: frags base 0,16 | mgrp1 base 32, keep l<36)
//   h1: l=0..33  <-> conv0 rows    t0-1+l     (C0: frags base 0,16 | mgrp1 base 18, keep l>=32)
//   w : l=0..31  <-> conv1 rows    t0+l       (C1: frag base mgrp*16)
// m_s[i] = mask at t0-2+i (0 outside [0,N_PH)) implements conv zero-padding.
__global__ __launch_bounds__(256, 4) void chain_kernel(
    const ushort_t* __restrict__ specT,
    const ushort_t* __restrict__ wpre, const ushort_t* __restrict__ w0t,
    const ushort_t* __restrict__ w1t,
    const float* __restrict__ pre_b, const float* __restrict__ c0_b,
    const float* __restrict__ c1_b,
    const float* __restrict__ mask,
    const float* __restrict__ g0, const float* __restrict__ be0,
    const float* __restrict__ g1, const float* __restrict__ be1,
    const float* __restrict__ lw, const float* __restrict__ lb,
    float* __restrict__ out)
{
    const int b  = blockIdx.y;
    const int t0 = blockIdx.x * TILE;
    const int tid = threadIdx.x;
    const int lane = tid & 63;
    const int wv = tid >> 6;
    const int nhalf = wv >> 1;          // output-channel half: cols nhalf*96..+95
    const int mgrp = wv & 1;            // M-frag group
    const int m = lane & 15;
    const int kg = (lane >> 4) << 3;
    const int rbase = (lane >> 4) << 2;

    __shared__ ushort_t hbuf[36 * HPITCH];          // 28.2 KB
    __shared__ float g0_s[H], b0_s[H], g1_s[H], b1_s[H];
    __shared__ float lw_s[OUT * H];
    __shared__ float m_s[36], mstat[34], rstat[34];

    if (tid < H) { g0_s[tid] = g0[tid]; b0_s[tid] = be0[tid];
                   g1_s[tid] = g1[tid]; b1_s[tid] = be1[tid]; }
    if (tid < 36) {
        int grow = t0 - 2 + tid;
        m_s[tid] = (grow >= 0 && grow < N_PH) ? mask[b * N_PH + grow] : 0.f;
    }
    for (int i = tid; i < OUT * H; i += 256) lw_s[i] = lw[i];
    __syncthreads();

    const short8 z8 = {0, 0, 0, 0, 0, 0, 0, 0};

    // ================= stage P: pre-linear (taps=1, K=192), 3 frags total ======
    {
        const int nf = mgrp ? 1 : 2;
        f32x4 acc[2][6];
#pragma unroll
        for (int n = 0; n < 6; ++n) {
            float bb = pre_b[(nhalf * 6 + n) * 16 + m];
            acc[0][n] = (f32x4){bb, bb, bb, bb};
            acc[1][n] = (f32x4){bb, bb, bb, bb};
        }
        const ushort_t* inb = specT + (size_t)b * N_PH * ROWP;
#pragma unroll 1
        for (int s = 0; s < 6; ++s) {
            short8 ah[2], al[2], bh[6], bl[6];
#pragma unroll
            for (int f = 0; f < 2; ++f) {
                if (f < nf) {
                    int fb = mgrp ? 32 : f * 16;
                    int trow = t0 - 2 + fb + m;
                    if ((unsigned)trow < (unsigned)N_PH) {
                        const ushort_t* ar = inb + (size_t)trow * ROWP + s * 32 + kg;
                        ah[f] = *(const short8*)ar;
                        al[f] = *(const short8*)(ar + H);
                    } else { ah[f] = z8; al[f] = z8; }
                }
            }
            const ushort_t* wb = wpre + ((size_t)(s * 12 + nhalf * 6) << 9) + (lane << 3);
#pragma unroll
            for (int n = 0; n < 6; ++n) {
                bh[n] = *(const short8*)(wb + (n << 9));
                bl[n] = *(const short8*)(wb + (n << 9) + 36864);
            }
#pragma unroll
            for (int f = 0; f < 2; ++f) {
                if (f < nf) {
#pragma unroll
                    for (int n = 0; n < 6; ++n) {
                        acc[f][n] = __builtin_amdgcn_mfma_f32_16x16x32_bf16(ah[f], bh[n], acc[f][n], 0, 0, 0);
                        acc[f][n] = __builtin_amdgcn_mfma_f32_16x16x32_bf16(al[f], bh[n], acc[f][n], 0, 0, 0);
                        acc[f][n] = __builtin_amdgcn_mfma_f32_16x16x32_bf16(ah[f], bl[n], acc[f][n], 0, 0, 0);
                    }
                }
            }
        }
        // store h0 = pre_out * mask, rows l < 36
#pragma unroll
        for (int f = 0; f < 2; ++f) {
            if (f < nf) {
                int fb = mgrp ? 32 : f * 16;
#pragma unroll
                for (int n = 0; n < 6; ++n) {
                    int col = (nhalf * 6 + n) * 16 + m;
#pragma unroll
                    for (int r = 0; r < 4; ++r) {
                        int l = fb + rbase + r;
                        if (l < 36) {
                            float v = acc[f][n][r] * m_s[l];
                            ushort_t hi, lo; split_bf(v, hi, lo);
                            hbuf[l * HPITCH + col] = hi;
                            hbuf[l * HPITCH + H + col] = lo;
                        }
                    }
                }
            }
        }
    }
    __syncthreads();

    // ================= stage C0: conv0 (taps=3), frag bases {0,16} | {18} ======
    {
        const int nf = mgrp ? 1 : 2;
        f32x4 acc[2][6];
#pragma unroll
        for (int n = 0; n < 6; ++n) {
            float bb = c0_b[(nhalf * 6 + n) * 16 + m];
            acc[0][n] = (f32x4){bb, bb, bb, bb};
            acc[1][n] = (f32x4){bb, bb, bb, bb};
        }
#pragma unroll 1
        for (int kt = 0; kt < 3; ++kt)
#pragma unroll 1
            for (int s = 0; s < 6; ++s) {
                short8 ah[2], al[2], bh[6], bl[6];
#pragma unroll
                for (int f = 0; f < 2; ++f) {
                    if (f < nf) {
                        int fb = mgrp ? 18 : f * 16;
                        int l0 = fb + m + kt;                // <= 35, inside h0
                        const ushort_t* ar = hbuf + l0 * HPITCH + s * 32 + kg;
                        ah[f] = *(const short8*)ar;
                        al[f] = *(const short8*)(ar + H);
                    }
                }
                const ushort_t* wb = w0t + ((size_t)((kt * 6 + s) * 12 + nhalf * 6) << 9) + (lane << 3);
#pragma unroll
                for (int n = 0; n < 6; ++n) {
                    bh[n] = *(const short8*)(wb + (n << 9));
                    bl[n] = *(const short8*)(wb + (n << 9) + 110592);
                }
#pragma unroll
                for (int f = 0; f < 2; ++f) {
                    if (f < nf) {
#pragma unroll
                        for (int n = 0; n < 6; ++n) {
                            acc[f][n] = __builtin_amdgcn_mfma_f32_16x16x32_bf16(ah[f], bh[n], acc[f][n], 0, 0, 0);
                            acc[f][n] = __builtin_amdgcn_mfma_f32_16x16x32_bf16(al[f], bh[n], acc[f][n], 0, 0, 0);
                            acc[f][n] = __builtin_amdgcn_mfma_f32_16x16x32_bf16(ah[f], bl[n], acc[f][n], 0, 0, 0);
                        }
                    }
                }
            }
        __syncthreads();   // all h0 reads complete before overwrite
        // store u = relu(v*m)*m into h1 rows l1<34; mgrp1 (base 18) keeps only l1>=32
#pragma unroll
        for (int f = 0; f < 2; ++f) {
            if (f < nf) {
                int fb = mgrp ? 18 : f * 16;
#pragma unroll
                for (int n = 0; n < 6; ++n) {
                    int col = (nhalf * 6 + n) * 16 + m;
#pragma unroll
                    for (int r = 0; r < 4; ++r) {
                        int l1 = fb + rbase + r;
                        bool keep = mgrp ? (l1 >= 32 && l1 < 34) : true;
                        if (keep) {
                            float mm = m_s[l1 + 1];
                            float u = fmaxf(acc[f][n][r] * mm, 0.f) * mm;
                            ushort_t hi, lo; split_bf(u, hi, lo);
                            hbuf[l1 * HPITCH + col] = hi;
                            hbuf[l1 * HPITCH + H + col] = lo;
                        }
                    }
                }
            }
        }
    }
    __syncthreads();

    // LN0 stats: 4 threads per row, vectorized short8 reads, shfl reduce
    {
        int row = tid >> 2;
        int q = tid & 3;
        if (row < 34) {
            float s = 0.f, ss = 0.f;
#pragma unroll
            for (int i = 0; i < 6; ++i) {
                int c0 = q * 48 + i * 8;
                short8 vh = *(const short8*)(hbuf + row * HPITCH + c0);
                short8 vl = *(const short8*)(hbuf + row * HPITCH + H + c0);
#pragma unroll
                for (int k2 = 0; k2 < 8; ++k2) {
                    float v = bf2f((ushort_t)vh[k2]) + bf2f((ushort_t)vl[k2]);
                    s += v; ss += v * v;
                }
            }
            s  += __shfl_xor(s, 1);  s  += __shfl_xor(s, 2);
            ss += __shfl_xor(ss, 1); ss += __shfl_xor(ss, 2);
            if (q == 0) {
                float mean = s * (1.f / (float)H);
                mstat[row] = mean;
                rstat[row] = rsqrtf(ss * (1.f / (float)H) - mean * mean + 1e-5f);
            }
        }
    }
    __syncthreads();
    // LN0 apply in place (vectorized), * mask^2
    for (int idx = tid; idx < 34 * 24; idx += 256) {
        int row = idx / 24;
        int c0 = (idx - row * 24) * 8;
        float mean = mstat[row], rstd = rstat[row];
        float mm = m_s[row + 1];
        float mm2 = mm * mm;
        short8 vh = *(const short8*)(hbuf + row * HPITCH + c0);
        short8 vl = *(const short8*)(hbuf + row * HPITCH + H + c0);
        ushort_t th[8], tl[8];
#pragma unroll
        for (int k2 = 0; k2 < 8; ++k2) {
            int c = c0 + k2;
            float v = bf2f((ushort_t)vh[k2]) + bf2f((ushort_t)vl[k2]);
            float y = ((v - mean) * rstd * g0_s[c] + b0_s[c]) * mm2;
            split_bf(y, th[k2], tl[k2]);
        }
        *(short8*)(hbuf + row * HPITCH + c0) = *(short8*)th;
        *(short8*)(hbuf + row * HPITCH + H + c0) = *(short8*)tl;
    }
    __syncthreads();

    // ================= stage C1: conv1 (taps=3), 1 frag per mgrp ======
    {
        f32x4 acc[6];
#pragma unroll
        for (int n = 0; n < 6; ++n) {
            float bb = c1_b[(nhalf * 6 + n) * 16 + m];
            acc[n] = (f32x4){bb, bb, bb, bb};
        }
#pragma unroll 1
        for (int kt = 0; kt < 3; ++kt)
#pragma unroll 1
            for (int s = 0; s < 6; ++s) {
                int l1 = mgrp * 16 + m + kt;                 // <= 33, inside h1
                const ushort_t* ar = hbuf + l1 * HPITCH + s * 32 + kg;
                short8 ah = *(const short8*)ar;
                short8 al = *(const short8*)(ar + H);
                const ushort_t* wb = w1t + ((size_t)((kt * 6 + s) * 12 + nhalf * 6) << 9) + (lane << 3);
                short8 bh[6], bl[6];
#pragma unroll
                for (int n = 0; n < 6; ++n) {
                    bh[n] = *(const short8*)(wb + (n << 9));
                    bl[n] = *(const short8*)(wb + (n << 9) + 110592);
                }
#pragma unroll
                for (int n = 0; n < 6; ++n) {
                    acc[n] = __builtin_amdgcn_mfma_f32_16x16x32_bf16(ah, bh[n], acc[n], 0, 0, 0);
                    acc[n] = __builtin_amdgcn_mfma_f32_16x16x32_bf16(al, bh[n], acc[n], 0, 0, 0);
                    acc[n] = __builtin_amdgcn_mfma_f32_16x16x32_bf16(ah, bl[n], acc[n], 0, 0, 0);
                }
            }
        __syncthreads();   // all h1 reads complete before overwrite
        // store w = relu(v*m)*m into rows 0..31
#pragma unroll
        for (int n = 0; n < 6; ++n) {
            int col = (nhalf * 6 + n) * 16 + m;
#pragma unroll
            for (int r = 0; r < 4; ++r) {
                int l2 = mgrp * 16 + rbase + r;              // < 32
                float mm = m_s[l2 + 2];
                float u = fmaxf(acc[n][r] * mm, 0.f) * mm;
                ushort_t hi, lo; split_bf(u, hi, lo);
                hbuf[l2 * HPITCH + col] = hi;
                hbuf[l2 * HPITCH + H + col] = lo;
            }
        }
    }
    __syncthreads();

    // LN1 stats: 4 threads per row (rows 0..31)
    {
        int row = tid >> 2;
        int q = tid & 3;
        if (row < 32) {
            float s = 0.f, ss = 0.f;
#pragma unroll
            for (int i = 0; i < 6; ++i) {
                int c0 = q * 48 + i * 8;
                short8 vh = *(const short8*)(hbuf + row * HPITCH + c0);
                short8 vl = *(const short8*)(hbuf + row * HPITCH + H + c0);
#pragma unroll
                for (int k2 = 0; k2 < 8; ++k2) {
                    float v = bf2f((ushort_t)vh[k2]) + bf2f((ushort_t)vl[k2]);
                    s += v; ss += v * v;
                }
            }
            s  += __shfl_xor(s, 1);  s  += __shfl_xor(s, 2);
            ss += __shfl_xor(ss, 1); ss += __shfl_xor(ss, 2);
            if (q == 0) {
                float mean = s * (1.f / (float)H);
                mstat[row] = mean;
                rstat[row] = rsqrtf(ss * (1.f / (float)H) - mean * mean + 1e-5f);
            }
        }
    }
    __syncthreads();

    // fused final projection: 8 threads per row, 24 chans each, shfl reduce
    {
        int row = tid >> 3;          // 0..31
        int q = tid & 7;
        float mean = mstat[row], rstd = rstat[row], mk = m_s[row + 2];
        float a0 = 0.f, a1 = 0.f, a2 = 0.f, a3 = 0.f;
#pragma unroll
        for (int i = 0; i < 3; ++i) {
            int c0 = q * 24 + i * 8;
            short8 vh = *(const short8*)(hbuf + row * HPITCH + c0);
            short8 vl = *(const short8*)(hbuf + row * HPITCH + H + c0);
#pragma unroll
            for (int k2 = 0; k2 < 8; ++k2) {
                int c = c0 + k2;
                float v = bf2f((ushort_t)vh[k2]) + bf2f((ushort_t)vl[k2]);
                float y = ((v - mean) * rstd * g1_s[c] + b1_s[c]) * mk;
                a0 += lw_s[0 * H + c] * y;
                a1 += lw_s[1 * H + c] * y;
                a2 += lw_s[2 * H + c] * y;
                a3 += lw_s[3 * H + c] * y;
            }
        }
        a0 += __shfl_xor(a0, 1); a0 += __shfl_xor(a0, 2); a0 += __shfl_xor(a0, 4);
        a1 += __shfl_xor(a1, 1); a1 += __shfl_xor(a1, 2); a1 += __shfl_xor(a1, 4);
        a2 += __shfl_xor(a2, 1); a2 += __shfl_xor(a2, 2); a2 += __shfl_xor(a2, 4);
        a3 += __shfl_xor(a3, 1); a3 += __shfl_xor(a3, 2); a3 += __shfl_xor(a3, 4);
        if (q == 0) {
            int t = t0 + row;
            float* ob = out + (size_t)b * OUT * N_PH + t;
            ob[0 * N_PH] = (a0 + lb[0]) * mk;
            ob[1 * N_PH] = (a1 + lb[1]) * mk;
            ob[2 * N_PH] = (a2 + lb[2]) * mk;
            ob[3 * N_PH] = (a3 + lb[3]) * mk;
        }
    }
}

extern "C" void kernel_launch(void* const* d_in, const int* in_sizes, int n_in,
                              void* d_out, int out_size, void* d_ws, size_t ws_size,
                              hipStream_t stream) {
    const float* x      = (const float*)d_in[0];
    const float* x_mask = (const float*)d_in[1];
    const int*   w      = (const int*)d_in[2];
    const float* pre_w  = (const float*)d_in[3];
    const float* pre_b  = (const float*)d_in[4];
    const float* conv0_w = (const float*)d_in[5];
    const float* conv0_b = (const float*)d_in[6];
    const float* ln0_g   = (const float*)d_in[7];
    const float* ln0_b   = (const float*)d_in[8];
    const float* conv1_w = (const float*)d_in[9];
    const float* conv1_b = (const float*)d_in[10];
    const float* ln1_g   = (const float*)d_in[11];
    const float* ln1_b   = (const float*)d_in[12];
    const float* lin_w   = (const float*)d_in[13];
    const float* lin_b   = (const float*)d_in[14];
    float* out = (float*)d_out;

    // workspace layout
    char* ws = (char*)d_ws;
    size_t off = 0;
    ushort_t* specT = (ushort_t*)(ws + off); off += (size_t)B * N_PH * ROWP * sizeof(ushort_t);
    ushort_t* wpre  = (ushort_t*)(ws + off); off += (size_t)2 * 36864 * sizeof(ushort_t);
    ushort_t* w0t   = (ushort_t*)(ws + off); off += (size_t)2 * 110592 * sizeof(ushort_t);
    ushort_t* w1t   = (ushort_t*)(ws + off); off += (size_t)2 * 110592 * sizeof(ushort_t);
    int* ends       = (int*)(ws + off);      off += (size_t)B * N_PH * sizeof(int);

    // weight fragments + per-batch duration scans, one dispatch
    prep_kernel<<<NWF + B, 256, 0, stream>>>(pre_w, conv0_w, conv1_w, w,
                                             wpre, w0t, w1t, ends);

    // segment mean -> time-major split bf16
    segmean_direct_kernel<<<B * 32, 256, 0, stream>>>(x, ends, specT);

    // whole post-segmean chain, one dispatch, independent 32-row tiles
    chain_kernel<<<dim3(N_PH / TILE, B), 256, 0, stream>>>(
        specT, wpre, w0t, w1t, pre_b, conv0_b, conv1_b, x_mask,
        ln0_g, ln0_b, ln1_g, ln1_b, lin_w, lin_b, out);
}